// Round 13
// baseline (236.047 us; speedup 1.0000x reference)
//
#include <hip/hip_runtime.h>

// MultiHeadAttention B=16 N=1024 E=768 H=8 D=96 — fp16 MFMA pipeline.
// ws layout (130.6 MB total):
//   WT   [3072][768] fp16 : rows 0-2303 = (Wq|Wk|Wv)^T, rows 2304-3071 = Wo^T
//   xh   [16384][768] fp16
//   QKV  [16384][2304] fp16 (cols: 0-767 Q, 768-1535 K, 1536-2303 V; head h at h*96)
//   Oh   [16384][768] fp16 (attention output, pre-projection)

typedef _Float16 half8 __attribute__((ext_vector_type(8)));
typedef __fp16 fp16x2 __attribute__((ext_vector_type(2)));
typedef float f32x4 __attribute__((ext_vector_type(4)));
typedef float f32x16 __attribute__((ext_vector_type(16)));

__device__ __forceinline__ void gload_lds16(const void* g, void* l) {
  __builtin_amdgcn_global_load_lds((const __attribute__((address_space(1))) void*)g,
                                   (__attribute__((address_space(3))) void*)l, 16, 0, 0);
}

// ---------------- converts ----------------

__global__ __launch_bounds__(256) void conv_x_kernel(const float* __restrict__ x,
                                                     _Float16* __restrict__ xh) {
  long i = ((long)blockIdx.x * 256 + threadIdx.x) * 8;
  float4 a = *(const float4*)(x + i);
  float4 b = *(const float4*)(x + i + 4);
  half8 o;
  o[0] = (_Float16)a.x; o[1] = (_Float16)a.y; o[2] = (_Float16)a.z; o[3] = (_Float16)a.w;
  o[4] = (_Float16)b.x; o[5] = (_Float16)b.y; o[6] = (_Float16)b.z; o[7] = (_Float16)b.w;
  *(half8*)(xh + i) = o;
}

__global__ __launch_bounds__(256) void transpose_cvt_kernel(
    const float* __restrict__ W0, const float* __restrict__ W1,
    const float* __restrict__ W2, const float* __restrict__ W3,
    _Float16* __restrict__ WT) {
  __shared__ float tile[32][33];
  int z = blockIdx.z;
  const float* W = (z == 0) ? W0 : (z == 1) ? W1 : (z == 2) ? W2 : W3;
  int k0 = blockIdx.y * 32, n0 = blockIdx.x * 32;
  int tx = threadIdx.x, ty = threadIdx.y;
#pragma unroll
  for (int j = ty; j < 32; j += 8)
    tile[j][tx] = W[(size_t)(k0 + j) * 768 + n0 + tx];
  __syncthreads();
  _Float16* dst = WT + (size_t)z * 768 * 768;
#pragma unroll
  for (int j = ty; j < 32; j += 8)
    dst[(size_t)(n0 + j) * 768 + k0 + tx] = (_Float16)tile[tx][j];
}

// ------ GEMM 256x256, BK=64, 8 waves (2Mx4N), m201-style 8-phase schedule ------
// C[M][ldc] = A[M][K]*Bt[N][K]^T + bias (3-way col select b0|b1|b2).
// LDS 128KB: As/Bs[2][256][64] fp16, seg-XOR swizzle seg^(row&7) (R12-proven pair:
// pre-swizzled global source + swizzled ds_read; gload_lds dest stays linear).
// Per K-tile: 4 phases. Phase p: ds_read A-quad p (4 b128; phase 0 also B-all 8)
// + stage(t+1) A-half (ph0) / B-half (ph1) -> barrier -> lgkmcnt(0) -> setprio(1)
// 16 MFMA -> setprio(0) -> [ph3: vmcnt(0) drains t+1, issued ~3 phases earlier]
// -> barrier. Cross-wave safety: per-wave vmcnt(0) + barrier = collective.

template <int OUT_F16>
__global__ __launch_bounds__(512) void gemm8p_kernel(
    const _Float16* __restrict__ A, const _Float16* __restrict__ Bt,
    const float* __restrict__ b0, const float* __restrict__ b1,
    const float* __restrict__ b2, void* __restrict__ C,
    int M, int N, int K, int ldc) {
  __shared__ _Float16 As[2][256 * 64];
  __shared__ _Float16 Bs[2][256 * 64];
  int nbx = N >> 8;
  int nwg = gridDim.x, wg = blockIdx.x;
  int cpx = nwg >> 3;                       // nwg % 8 == 0 guaranteed by launch
  int swz = (wg & 7) * cpx + (wg >> 3);     // XCD-aware bijective swizzle
  int bx = swz % nbx, by = swz / nbx;
  int m0 = by * 256, n0 = bx * 256;
  int t = threadIdx.x, l = t & 63, w = t >> 6;
  int lg = l >> 4, lr = l & 15;
  int wm = w >> 2, wn = w & 3;              // wave C block: rows wm*128, cols wn*64
  f32x4 acc[8][4] = {};                     // [frag-row 0..7][frag-col 0..3]

  // staging: slot s = j*512+t -> row s>>3 (0..255), seg s&7; source pre-swizzled
  int srow[4], ssc[4];
#pragma unroll
  for (int j = 0; j < 4; ++j) {
    int s = j * 512 + t;
    srow[j] = s >> 3;
    ssc[j] = ((s & 7) ^ (srow[j] & 7)) * 8;
  }

  auto stageA = [&](int kt, int c) {
    int k0 = kt * 64;
#pragma unroll
    for (int j = 0; j < 4; ++j)
      gload_lds16(A + (size_t)(m0 + srow[j]) * K + k0 + ssc[j], &As[c][(j * 512 + t) * 8]);
  };
  auto stageB = [&](int kt, int c) {
    int k0 = kt * 64;
#pragma unroll
    for (int j = 0; j < 4; ++j)
      gload_lds16(Bt + (size_t)(n0 + srow[j]) * K + k0 + ssc[j], &Bs[c][(j * 512 + t) * 8]);
  };

  // prologue: stage tile 0, full drain
  stageA(0, 0); stageB(0, 0);
  asm volatile("s_waitcnt vmcnt(0)" ::: "memory");
  __builtin_amdgcn_sched_barrier(0);
  __builtin_amdgcn_s_barrier();

  int nkt = K >> 6;
  for (int kt = 0; kt < nkt; ++kt) {
    int c = kt & 1;
    bool pre = (kt + 1) < nkt;
    half8 bf[4][2];
#pragma unroll
    for (int qd = 0; qd < 4; ++qd) {
      half8 af[2][2];
      // --- ds-load this phase's A quad (+ B all in phase 0)
      if (qd == 0) {
#pragma unroll
        for (int fc = 0; fc < 4; ++fc)
#pragma unroll
          for (int kk = 0; kk < 2; ++kk) {
            int row = wn * 64 + fc * 16 + lr;
            bf[fc][kk] = *(const half8*)&Bs[c][row * 64 + (((kk * 4 + lg) ^ (row & 7)) * 8)];
          }
      }
#pragma unroll
      for (int f2 = 0; f2 < 2; ++f2)
#pragma unroll
        for (int kk = 0; kk < 2; ++kk) {
          int row = wm * 128 + (qd * 2 + f2) * 16 + lr;
          af[f2][kk] = *(const half8*)&As[c][row * 64 + (((kk * 4 + lg) ^ (row & 7)) * 8)];
        }
      // --- stage next tile: A-half in phase 0, B-half in phase 1
      if (qd == 0 && pre) stageA(kt + 1, c ^ 1);
      if (qd == 1 && pre) stageB(kt + 1, c ^ 1);
      __builtin_amdgcn_sched_barrier(0);
      __builtin_amdgcn_s_barrier();
      asm volatile("s_waitcnt lgkmcnt(0)" ::: "memory");
      __builtin_amdgcn_sched_barrier(0);
      __builtin_amdgcn_s_setprio(1);
#pragma unroll
      for (int f2 = 0; f2 < 2; ++f2)
#pragma unroll
        for (int fc = 0; fc < 4; ++fc)
#pragma unroll
          for (int kk = 0; kk < 2; ++kk)
            acc[qd * 2 + f2][fc] = __builtin_amdgcn_mfma_f32_16x16x32_f16(
                af[f2][kk], bf[fc][kk], acc[qd * 2 + f2][fc], 0, 0, 0);
      __builtin_amdgcn_s_setprio(0);
      __builtin_amdgcn_sched_barrier(0);
      if (qd == 3) {  // tile kt+1 (issued phases 0-1, ~3 phases of cover) must land
        asm volatile("s_waitcnt vmcnt(0)" ::: "memory");
        __builtin_amdgcn_sched_barrier(0);
      }
      __builtin_amdgcn_s_barrier();
    }
  }

  // epilogue: D col=lane&15, row=4*(lane>>4)+i per 16x16 frag
#pragma unroll
  for (int fr = 0; fr < 8; ++fr)
#pragma unroll
    for (int fc = 0; fc < 4; ++fc) {
      int col = n0 + wn * 64 + fc * 16 + lr;
      float bb = (col < 768) ? b0[col] : (col < 1536) ? b1[col - 768] : b2[col - 1536];
#pragma unroll
      for (int i = 0; i < 4; ++i) {
        int row = m0 + wm * 128 + fr * 16 + lg * 4 + i;
        float v = acc[fr][fc][i] + bb;
        if (OUT_F16)
          ((_Float16*)C)[(size_t)row * ldc + col] = (_Float16)v;
        else
          ((float*)C)[(size_t)row * ldc + col] = v;
      }
    }
}

// ---------------- flash attention: 32x32 MFMA, in-register P (R12, unchanged) ----

__global__ __launch_bounds__(256, 2) void attn_kernel(const _Float16* __restrict__ QKV,
                                                      _Float16* __restrict__ Oh) {
  int hw = blockIdx.x;
  int lin = (hw & 7) * 128 + (hw >> 3);   // XCD-chunked
  int bh = lin >> 3, qt = lin & 7;
  int b = bh >> 3, h = bh & 7;
  int t = threadIdx.x, w = t >> 6, l = t & 63;
  int lr = l & 31, hi = l >> 5;

  __shared__ __align__(16) char KF[2][12288];
  __shared__ __align__(16) _Float16 VF[2][96 * 64];

  const _Float16* Qb = QKV + (size_t)b * 1024 * 2304 + h * 96;
  const _Float16* Kb = Qb + 768;
  const _Float16* Vb = Qb + 1536;

  half8 qf[6];
  {
    int qrow = qt * 128 + w * 32 + lr;
    const _Float16 s = (_Float16)1.4426950408889634f;  // LOG2E folded into Q
#pragma unroll
    for (int c = 0; c < 6; ++c) {
      qf[c] = *(const half8*)&Qb[(size_t)qrow * 2304 + c * 16 + hi * 8];
#pragma unroll
      for (int e = 0; e < 8; ++e) qf[c][e] = qf[c][e] * s;
    }
  }

  int ks_src[3], ks_dst[3];
#pragma unroll
  for (int j = 0; j < 3; ++j) {
    int s = j * 256 + t;
    int f = s >> 6, lane = s & 63;
    int sb = f / 6, c = f - sb * 6;
    ks_src[j] = (sb * 32 + (lane & 31)) * 2304 + c * 16 + ((lane >> 5) & 1) * 8;
    ks_dst[j] = s * 16;
  }
  bool vact[2];
  int v_src[2], v_dst[2][8];
#pragma unroll
  for (int j = 0; j < 2; ++j) {
    int u = j * 256 + t;
    vact[j] = u < 384;
    int kvp = u / 12, mm = u % 12;
    v_src[j] = 2 * kvp * 2304 + mm * 8;
#pragma unroll
    for (int e = 0; e < 8; ++e) {
      int d = mm * 8 + e;
      int sw = ((d & 7) ^ ((d >> 3) & 7)) << 3;
      v_dst[j][e] = d * 64 + ((2 * kvp) ^ sw);
    }
  }

  auto stage_K = [&](int kv0, int bi) {
    size_t goff = (size_t)kv0 * 2304;
#pragma unroll
    for (int j = 0; j < 3; ++j)
      gload_lds16(Kb + goff + ks_src[j], &KF[bi][ks_dst[j]]);
  };

  half8 vr0[2], vr1[2];                   // in-flight V tile (T14 split)
  auto loadV = [&](int kv0) {
    size_t goff = (size_t)kv0 * 2304;
#pragma unroll
    for (int j = 0; j < 2; ++j)
      if (vact[j]) {
        const _Float16* vp = Vb + goff + v_src[j];
        vr0[j] = *(const half8*)vp;
        vr1[j] = *(const half8*)(vp + 2304);
      }
  };
  auto writeV = [&](int bi) {
#pragma unroll
    for (int j = 0; j < 2; ++j)
      if (vact[j]) {
#pragma unroll
        for (int e = 0; e < 8; ++e) {
          union { _Float16 h2[2]; unsigned u32; } pk;
          pk.h2[0] = vr0[j][e]; pk.h2[1] = vr1[j][e];
          *(unsigned*)&VF[bi][v_dst[j][e]] = pk.u32;
        }
      }
  };

  half8 vones;
#pragma unroll
  for (int e = 0; e < 8; ++e) vones[e] = (_Float16)1.0f;

  float m_run = -3.0e38f;
  f32x16 oa[3] = {};
  f32x16 lacc = {};

  stage_K(0, 0);
  loadV(0);
  writeV(0);

  for (int tile = 0; tile < 16; ++tile) {
    int bi = tile & 1;
    __syncthreads();
    if (tile + 1 < 16) {
      stage_K((tile + 1) * 64, bi ^ 1);
      loadV((tile + 1) * 64);
      __builtin_amdgcn_sched_barrier(0);
    }

    f32x16 sA[2] = {};
#pragma unroll
    for (int sb = 0; sb < 2; ++sb)
#pragma unroll
      for (int c = 0; c < 6; ++c) {
        half8 kf = *(const half8*)(KF[bi] + (sb * 6 + c) * 1024 + l * 16);
        sA[sb] = __builtin_amdgcn_mfma_f32_32x32x16_f16(kf, qf[c], sA[sb], 0, 0, 0);
      }

    float tmax = -3.0e38f;
#pragma unroll
    for (int sb = 0; sb < 2; ++sb)
#pragma unroll
      for (int r = 0; r < 16; ++r) tmax = fmaxf(tmax, sA[sb][r]);
    tmax = fmaxf(tmax, __shfl_xor(tmax, 32, 64));

    if (!__all(tmax <= m_run + 11.5f)) {
      float m_new = fmaxf(m_run, tmax);
      float scale = __builtin_exp2f(m_run - m_new);
#pragma unroll
      for (int r = 0; r < 16; ++r) {
        float sr = __shfl(scale, (r & 3) + 8 * (r >> 2) + 4 * hi, 64);
        oa[0][r] *= sr; oa[1][r] *= sr; oa[2][r] *= sr;
        lacc[r] *= sr;
      }
      m_run = m_new;
    }

    unsigned keep[8], send[8];
#pragma unroll
    for (int sb = 0; sb < 2; ++sb) {
      float e[16];
#pragma unroll
      for (int r = 0; r < 16; ++r) e[r] = __builtin_exp2f(sA[sb][r] - m_run);
      unsigned w32[8];
#pragma unroll
      for (int p = 0; p < 4; ++p)
#pragma unroll
        for (int m = 0; m < 2; ++m) {
          union { fp16x2 h2; unsigned u; } pk;
          pk.h2 = __builtin_amdgcn_cvt_pkrtz(e[4 * p + 2 * m], e[4 * p + 2 * m + 1]);
          w32[p * 2 + m] = pk.u;
        }
#pragma unroll
      for (int kb = 0; kb < 2; ++kb)
#pragma unroll
        for (int m = 0; m < 2; ++m) {
          keep[sb * 4 + kb * 2 + m] = hi ? w32[(2 * kb + 1) * 2 + m] : w32[(2 * kb) * 2 + m];
          send[sb * 4 + kb * 2 + m] = hi ? w32[(2 * kb) * 2 + m] : w32[(2 * kb + 1) * 2 + m];
        }
    }

    unsigned recv[8];
#pragma unroll
    for (int i = 0; i < 8; ++i) recv[i] = __shfl_xor(send[i], 32, 64);

#pragma unroll
    for (int kstep = 0; kstep < 4; ++kstep) {
      int base = (kstep >> 1) * 4 + (kstep & 1) * 2;
      union { unsigned u[4]; half8 h8; } pa;
      pa.u[0] = hi ? recv[base + 0] : keep[base + 0];
      pa.u[1] = hi ? recv[base + 1] : keep[base + 1];
      pa.u[2] = hi ? keep[base + 0] : recv[base + 0];
      pa.u[3] = hi ? keep[base + 1] : recv[base + 1];
#pragma unroll
      for (int dt = 0; dt < 3; ++dt) {
        int d = dt * 32 + lr;
        int sw = ((d & 7) ^ ((d >> 3) & 7)) << 3;
        half8 vf = *(const half8*)&VF[bi][d * 64 + ((kstep * 16 + hi * 8) ^ sw)];
        oa[dt] = __builtin_amdgcn_mfma_f32_32x32x16_f16(pa.h8, vf, oa[dt], 0, 0, 0);
      }
      lacc = __builtin_amdgcn_mfma_f32_32x32x16_f16(pa.h8, vones, lacc, 0, 0, 0);
    }

    if (tile + 1 < 16) writeV(bi ^ 1);
  }

  size_t rbase = (size_t)(b * 1024 + qt * 128 + w * 32) * 768 + h * 96;
#pragma unroll
  for (int r = 0; r < 16; ++r) {
    int q = (r & 3) + 8 * (r >> 2) + 4 * hi;
    float ivr = 1.0f / (lacc[r] * 27.712812921102035f);
#pragma unroll
    for (int dt = 0; dt < 3; ++dt)
      Oh[rbase + (size_t)q * 768 + dt * 32 + lr] = (_Float16)(oa[dt][r] * ivr);
  }
}

// ---------------- launch ----------------

extern "C" void kernel_launch(void* const* d_in, const int* in_sizes, int n_in,
                              void* d_out, int out_size, void* d_ws, size_t ws_size,
                              hipStream_t stream) {
  const float* x  = (const float*)d_in[0];
  const float* Wq = (const float*)d_in[1];
  const float* bq = (const float*)d_in[2];
  const float* Wk = (const float*)d_in[3];
  const float* bk = (const float*)d_in[4];
  const float* Wv = (const float*)d_in[5];
  const float* bv = (const float*)d_in[6];
  const float* Wo = (const float*)d_in[7];
  const float* bo = (const float*)d_in[8];
  float* out = (float*)d_out;

  char* ws = (char*)d_ws;
  _Float16* WT   = (_Float16*)(ws);                // 4,718,592 B
  _Float16* xh   = (_Float16*)(ws + 4751360);      // 25,165,824 B
  _Float16* QKV  = (_Float16*)(ws + 29917184);     // 75,497,472 B
  _Float16* Oh   = (_Float16*)(ws + 105414656);    // 25,165,824 B  (total ~130.6 MB)

  conv_x_kernel<<<6144, 256, 0, stream>>>(x, xh);
  transpose_cvt_kernel<<<dim3(24, 24, 4), dim3(32, 8), 0, stream>>>(Wq, Wk, Wv, Wo, WT);

  // QKV: M=16384, N=2304, K=768 -> grid (16384/256)*(2304/256) = 64*9 = 576
  gemm8p_kernel<1><<<576, 512, 0, stream>>>(xh, WT, bq, bk, bv, QKV,
                                            16384, 2304, 768, 2304);

  attn_kernel<<<1024, 256, 0, stream>>>(QKV, Oh);

  // out-proj: M=16384, N=768, K=768 -> grid 64*3 = 192
  gemm8p_kernel<0><<<192, 512, 0, stream>>>(Oh, WT + (size_t)2304 * 768, bo, bo, bo, out,
                                            16384, 768, 768, 768);
}

// Round 15
// 227.496 us; speedup vs baseline: 1.0376x; 1.0376x over previous
//
#include <hip/hip_runtime.h>

// MultiHeadAttention B=16 N=1024 E=768 H=8 D=96 — fp16 MFMA pipeline.
// ws layout (130.6 MB total):
//   WT   [3072][768] fp16 : rows 0-2303 = (Wq|Wk|Wv)^T, rows 2304-3071 = Wo^T
//   xh   [16384][768] fp16
//   QKV  [16384][2304] fp16 (cols: 0-767 Q, 768-1535 K, 1536-2303 V; head h at h*96)
//   Oh   [16384][768] fp16 (attention output, pre-projection)
// R15 = exact revert to R12 (best verified: 227.4 us).

typedef _Float16 half8 __attribute__((ext_vector_type(8)));
typedef __fp16 fp16x2 __attribute__((ext_vector_type(2)));
typedef float f32x4 __attribute__((ext_vector_type(4)));
typedef float f32x16 __attribute__((ext_vector_type(16)));

__device__ __forceinline__ void gload_lds16(const void* g, void* l) {
  __builtin_amdgcn_global_load_lds((const __attribute__((address_space(1))) void*)g,
                                   (__attribute__((address_space(3))) void*)l, 16, 0, 0);
}

// ---------------- converts ----------------

__global__ __launch_bounds__(256) void conv_x_kernel(const float* __restrict__ x,
                                                     _Float16* __restrict__ xh) {
  long i = ((long)blockIdx.x * 256 + threadIdx.x) * 8;
  float4 a = *(const float4*)(x + i);
  float4 b = *(const float4*)(x + i + 4);
  half8 o;
  o[0] = (_Float16)a.x; o[1] = (_Float16)a.y; o[2] = (_Float16)a.z; o[3] = (_Float16)a.w;
  o[4] = (_Float16)b.x; o[5] = (_Float16)b.y; o[6] = (_Float16)b.z; o[7] = (_Float16)b.w;
  *(half8*)(xh + i) = o;
}

__global__ __launch_bounds__(256) void transpose_cvt_kernel(
    const float* __restrict__ W0, const float* __restrict__ W1,
    const float* __restrict__ W2, const float* __restrict__ W3,
    _Float16* __restrict__ WT) {
  __shared__ float tile[32][33];
  int z = blockIdx.z;
  const float* W = (z == 0) ? W0 : (z == 1) ? W1 : (z == 2) ? W2 : W3;
  int k0 = blockIdx.y * 32, n0 = blockIdx.x * 32;
  int tx = threadIdx.x, ty = threadIdx.y;
#pragma unroll
  for (int j = ty; j < 32; j += 8)
    tile[j][tx] = W[(size_t)(k0 + j) * 768 + n0 + tx];
  __syncthreads();
  _Float16* dst = WT + (size_t)z * 768 * 768;
#pragma unroll
  for (int j = ty; j < 32; j += 8)
    dst[(size_t)(n0 + j) * 768 + k0 + tx] = (_Float16)tile[tx][j];
}

// ---------------- GEMM: C[M][ldc] = A[M][K] * Bt[N][K]^T + bias ----------------
// m97 structure, BK=64: 128x128 tile, 4 waves, global_load_lds w=16, 2 barriers
// per K-step (12 steps at K=768), seg-XOR swizzle pair (pre-swizzled global
// source + swizzled ds_read), XCD-swizzled 1D grid, fused 3-way bias select.

template <int OUT_F16>
__global__ __launch_bounds__(256) void gemm_nt_kernel(
    const _Float16* __restrict__ A, const _Float16* __restrict__ Bt,
    const float* __restrict__ b0, const float* __restrict__ b1,
    const float* __restrict__ b2, void* __restrict__ C,
    int M, int N, int K, int ldc) {
  __shared__ _Float16 As[128 * 64];
  __shared__ _Float16 Bs[128 * 64];
  int nbx = N >> 7;
  int nwg = gridDim.x;
  int wg = blockIdx.x;
  int cpx = nwg >> 3;                       // nwg % 8 == 0 guaranteed by launch
  int swz = (wg & 7) * cpx + (wg >> 3);     // XCD-aware bijective swizzle
  int bx = swz % nbx, by = swz / nbx;
  int m0 = by * 128, n0 = bx * 128;
  int t = threadIdx.x, l = t & 63, w = t >> 6;
  int lg = l >> 4, lr = l & 15;
  int wr = w >> 1, wc = w & 1;
  f32x4 acc[4][4] = {};

  int srow[4], ssc[4];
#pragma unroll
  for (int j = 0; j < 4; ++j) {
    int s = j * 256 + t;
    srow[j] = s >> 3;
    ssc[j] = ((s & 7) ^ (srow[j] & 7)) * 8;   // pre-swizzled source column (elems)
  }

  for (int k0 = 0; k0 < K; k0 += 64) {
    __syncthreads();  // previous compute done before overwrite
#pragma unroll
    for (int j = 0; j < 4; ++j)
      gload_lds16(A + (size_t)(m0 + srow[j]) * K + k0 + ssc[j], &As[(j * 256 + t) * 8]);
#pragma unroll
    for (int j = 0; j < 4; ++j)
      gload_lds16(Bt + (size_t)(n0 + srow[j]) * K + k0 + ssc[j], &Bs[(j * 256 + t) * 8]);
    __syncthreads();  // drains vmcnt -> tiles ready

#pragma unroll
    for (int kk = 0; kk < 2; ++kk) {
      half8 af[4], bf[4];
#pragma unroll
      for (int r = 0; r < 4; ++r) {
        int row = wr * 64 + r * 16 + lr;
        af[r] = *(const half8*)&As[row * 64 + (((kk * 4 + lg) ^ (row & 7)) * 8)];
      }
#pragma unroll
      for (int c = 0; c < 4; ++c) {
        int row = wc * 64 + c * 16 + lr;
        bf[c] = *(const half8*)&Bs[row * 64 + (((kk * 4 + lg) ^ (row & 7)) * 8)];
      }
#pragma unroll
      for (int r = 0; r < 4; ++r)
#pragma unroll
        for (int c = 0; c < 4; ++c)
          acc[r][c] = __builtin_amdgcn_mfma_f32_16x16x32_f16(af[r], bf[c], acc[r][c], 0, 0, 0);
    }
  }

#pragma unroll
  for (int r = 0; r < 4; ++r)
#pragma unroll
    for (int c = 0; c < 4; ++c) {
      int col = n0 + wc * 64 + c * 16 + lr;
      float bb = (col < 768) ? b0[col] : (col < 1536) ? b1[col - 768] : b2[col - 1536];
#pragma unroll
      for (int i = 0; i < 4; ++i) {
        int row = m0 + wr * 64 + r * 16 + lg * 4 + i;  // D: col=lane&15, row=4*(lane>>4)+i
        float v = acc[r][c][i] + bb;
        if (OUT_F16)
          ((_Float16*)C)[(size_t)row * ldc + col] = (_Float16)v;
        else
          ((float*)C)[(size_t)row * ldc + col] = v;
      }
    }
}

// ---------------- flash attention: 32x32 MFMA, in-register P (R12) ----------------
// Grid 1024 XCD-chunked, 256 thr = 4 waves, wave owns 32 q rows (QBLK=128),
// KVBLK=64, double-buffered, LDS 48KB, launch_bounds(256,2).
// KF fragment-major (conflict-free b128); VF scatter layout with d-XOR swizzle.
// P in registers (rule #20-safe constant indexing), lane<->lane^32 via shfl_xor.
// T14 async-STAGE split for V; row-sum l via ones-MFMA (lacc).
// Q pre-scaled by LOG2E; defer-max THR=11.5; O /= (l * sqrt(768)).

__global__ __launch_bounds__(256, 2) void attn_kernel(const _Float16* __restrict__ QKV,
                                                      _Float16* __restrict__ Oh) {
  int hw = blockIdx.x;
  int lin = (hw & 7) * 128 + (hw >> 3);   // XCD-chunked
  int bh = lin >> 3, qt = lin & 7;
  int b = bh >> 3, h = bh & 7;
  int t = threadIdx.x, w = t >> 6, l = t & 63;
  int lr = l & 31, hi = l >> 5;

  __shared__ __align__(16) char KF[2][12288];
  __shared__ __align__(16) _Float16 VF[2][96 * 64];

  const _Float16* Qb = QKV + (size_t)b * 1024 * 2304 + h * 96;
  const _Float16* Kb = Qb + 768;
  const _Float16* Vb = Qb + 1536;

  half8 qf[6];
  {
    int qrow = qt * 128 + w * 32 + lr;
    const _Float16 s = (_Float16)1.4426950408889634f;  // LOG2E folded into Q
#pragma unroll
    for (int c = 0; c < 6; ++c) {
      qf[c] = *(const half8*)&Qb[(size_t)qrow * 2304 + c * 16 + hi * 8];
#pragma unroll
      for (int e = 0; e < 8; ++e) qf[c][e] = qf[c][e] * s;
    }
  }

  int ks_src[3], ks_dst[3];
#pragma unroll
  for (int j = 0; j < 3; ++j) {
    int s = j * 256 + t;
    int f = s >> 6, lane = s & 63;
    int sb = f / 6, c = f - sb * 6;
    ks_src[j] = (sb * 32 + (lane & 31)) * 2304 + c * 16 + ((lane >> 5) & 1) * 8;
    ks_dst[j] = s * 16;
  }
  bool vact[2];
  int v_src[2], v_dst[2][8];
#pragma unroll
  for (int j = 0; j < 2; ++j) {
    int u = j * 256 + t;
    vact[j] = u < 384;
    int kvp = u / 12, mm = u % 12;
    v_src[j] = 2 * kvp * 2304 + mm * 8;
#pragma unroll
    for (int e = 0; e < 8; ++e) {
      int d = mm * 8 + e;
      int sw = ((d & 7) ^ ((d >> 3) & 7)) << 3;
      v_dst[j][e] = d * 64 + ((2 * kvp) ^ sw);
    }
  }

  auto stage_K = [&](int kv0, int bi) {
    size_t goff = (size_t)kv0 * 2304;
#pragma unroll
    for (int j = 0; j < 3; ++j)
      gload_lds16(Kb + goff + ks_src[j], &KF[bi][ks_dst[j]]);
  };

  half8 vr0[2], vr1[2];                   // in-flight V tile (T14 split)
  auto loadV = [&](int kv0) {
    size_t goff = (size_t)kv0 * 2304;
#pragma unroll
    for (int j = 0; j < 2; ++j)
      if (vact[j]) {
        const _Float16* vp = Vb + goff + v_src[j];
        vr0[j] = *(const half8*)vp;
        vr1[j] = *(const half8*)(vp + 2304);
      }
  };
  auto writeV = [&](int bi) {
#pragma unroll
    for (int j = 0; j < 2; ++j)
      if (vact[j]) {
#pragma unroll
        for (int e = 0; e < 8; ++e) {
          union { _Float16 h2[2]; unsigned u32; } pk;
          pk.h2[0] = vr0[j][e]; pk.h2[1] = vr1[j][e];
          *(unsigned*)&VF[bi][v_dst[j][e]] = pk.u32;
        }
      }
  };

  half8 vones;
#pragma unroll
  for (int e = 0; e < 8; ++e) vones[e] = (_Float16)1.0f;

  float m_run = -3.0e38f;
  f32x16 oa[3] = {};   // O: col d = dt*32+lr, row q = (reg&3)+8*(reg>>2)+4*hi
  f32x16 lacc = {};    // row-sum of P (same row mapping), via ones-MFMA

  stage_K(0, 0);
  loadV(0);
  writeV(0);

  for (int tile = 0; tile < 16; ++tile) {
    int bi = tile & 1;
    __syncthreads();
    if (tile + 1 < 16) {
      stage_K((tile + 1) * 64, bi ^ 1);
      loadV((tile + 1) * 64);
      __builtin_amdgcn_sched_barrier(0);
    }

    f32x16 sA[2] = {};
#pragma unroll
    for (int sb = 0; sb < 2; ++sb)
#pragma unroll
      for (int c = 0; c < 6; ++c) {
        half8 kf = *(const half8*)(KF[bi] + (sb * 6 + c) * 1024 + l * 16);
        sA[sb] = __builtin_amdgcn_mfma_f32_32x32x16_f16(kf, qf[c], sA[sb], 0, 0, 0);
      }

    float tmax = -3.0e38f;
#pragma unroll
    for (int sb = 0; sb < 2; ++sb)
#pragma unroll
      for (int r = 0; r < 16; ++r) tmax = fmaxf(tmax, sA[sb][r]);
    tmax = fmaxf(tmax, __shfl_xor(tmax, 32, 64));

    if (!__all(tmax <= m_run + 11.5f)) {
      float m_new = fmaxf(m_run, tmax);
      float scale = __builtin_exp2f(m_run - m_new);
#pragma unroll
      for (int r = 0; r < 16; ++r) {
        float sr = __shfl(scale, (r & 3) + 8 * (r >> 2) + 4 * hi, 64);
        oa[0][r] *= sr; oa[1][r] *= sr; oa[2][r] *= sr;
        lacc[r] *= sr;
      }
      m_run = m_new;
    }

    unsigned keep[8], send[8];
#pragma unroll
    for (int sb = 0; sb < 2; ++sb) {
      float e[16];
#pragma unroll
      for (int r = 0; r < 16; ++r) e[r] = __builtin_exp2f(sA[sb][r] - m_run);
      unsigned w32[8];
#pragma unroll
      for (int p = 0; p < 4; ++p)
#pragma unroll
        for (int m = 0; m < 2; ++m) {
          union { fp16x2 h2; unsigned u; } pk;
          pk.h2 = __builtin_amdgcn_cvt_pkrtz(e[4 * p + 2 * m], e[4 * p + 2 * m + 1]);
          w32[p * 2 + m] = pk.u;
        }
#pragma unroll
      for (int kb = 0; kb < 2; ++kb)
#pragma unroll
        for (int m = 0; m < 2; ++m) {
          keep[sb * 4 + kb * 2 + m] = hi ? w32[(2 * kb + 1) * 2 + m] : w32[(2 * kb) * 2 + m];
          send[sb * 4 + kb * 2 + m] = hi ? w32[(2 * kb) * 2 + m] : w32[(2 * kb + 1) * 2 + m];
        }
    }

    unsigned recv[8];
#pragma unroll
    for (int i = 0; i < 8; ++i) recv[i] = __shfl_xor(send[i], 32, 64);

#pragma unroll
    for (int kstep = 0; kstep < 4; ++kstep) {
      int base = (kstep >> 1) * 4 + (kstep & 1) * 2;
      union { unsigned u[4]; half8 h8; } pa;
      pa.u[0] = hi ? recv[base + 0] : keep[base + 0];
      pa.u[1] = hi ? recv[base + 1] : keep[base + 1];
      pa.u[2] = hi ? keep[base + 0] : recv[base + 0];
      pa.u[3] = hi ? keep[base + 1] : recv[base + 1];
#pragma unroll
      for (int dt = 0; dt < 3; ++dt) {
        int d = dt * 32 + lr;
        int sw = ((d & 7) ^ ((d >> 3) & 7)) << 3;
        half8 vf = *(const half8*)&VF[bi][d * 64 + ((kstep * 16 + hi * 8) ^ sw)];
        oa[dt] = __builtin_amdgcn_mfma_f32_32x32x16_f16(pa.h8, vf, oa[dt], 0, 0, 0);
      }
      lacc = __builtin_amdgcn_mfma_f32_32x32x16_f16(pa.h8, vones, lacc, 0, 0, 0);
    }

    if (tile + 1 < 16) writeV(bi ^ 1);
  }

  size_t rbase = (size_t)(b * 1024 + qt * 128 + w * 32) * 768 + h * 96;
#pragma unroll
  for (int r = 0; r < 16; ++r) {
    int q = (r & 3) + 8 * (r >> 2) + 4 * hi;
    float ivr = 1.0f / (lacc[r] * 27.712812921102035f);
#pragma unroll
    for (int dt = 0; dt < 3; ++dt)
      Oh[rbase + (size_t)q * 768 + dt * 32 + lr] = (_Float16)(oa[dt][r] * ivr);
  }
}

// ---------------- launch ----------------

extern "C" void kernel_launch(void* const* d_in, const int* in_sizes, int n_in,
                              void* d_out, int out_size, void* d_ws, size_t ws_size,
                              hipStream_t stream) {
  const float* x  = (const float*)d_in[0];
  const float* Wq = (const float*)d_in[1];
  const float* bq = (const float*)d_in[2];
  const float* Wk = (const float*)d_in[3];
  const float* bk = (const float*)d_in[4];
  const float* Wv = (const float*)d_in[5];
  const float* bv = (const float*)d_in[6];
  const float* Wo = (const float*)d_in[7];
  const float* bo = (const float*)d_in[8];
  float* out = (float*)d_out;

  char* ws = (char*)d_ws;
  _Float16* WT   = (_Float16*)(ws);                // 4,718,592 B
  _Float16* xh   = (_Float16*)(ws + 4751360);      // 25,165,824 B
  _Float16* QKV  = (_Float16*)(ws + 29917184);     // 75,497,472 B
  _Float16* Oh   = (_Float16*)(ws + 105414656);    // 25,165,824 B  (total ~130.6 MB)

  conv_x_kernel<<<6144, 256, 0, stream>>>(x, xh);
  transpose_cvt_kernel<<<dim3(24, 24, 4), dim3(32, 8), 0, stream>>>(Wq, Wk, Wv, Wo, WT);

  // QKV: M=16384, N=2304, K=768 -> grid 128*18 = 2304 (3 exact rounds of 768)
  gemm_nt_kernel<1><<<2304, 256, 0, stream>>>(xh, WT, bq, bk, bv, QKV,
                                              16384, 2304, 768, 2304);

  attn_kernel<<<1024, 256, 0, stream>>>(QKV, Oh);

  // out-proj: M=16384, N=768, K=768 -> grid 128*6 = 768 (1 exact round)
  gemm_nt_kernel<0><<<768, 256, 0, stream>>>(Oh, WT + (size_t)2304 * 768, bo, bo, bo, out,
                                             16384, 768, 768, 768);
}